// Round 3
// baseline (339.421 us; speedup 1.0000x reference)
//
#include <hip/hip_runtime.h>

#define N_  8
#define C_  3
#define HD_ 1024
#define WD_ 1280
#define HS_ 800
#define WS_ 1280

typedef _Float16 h2_t __attribute__((ext_vector_type(2)));
typedef float f32x4 __attribute__((ext_vector_type(4)));

__device__ __forceinline__ unsigned pack_h2(float a, float b) {
    h2_t h;
    h.x = (_Float16)a;
    h.y = (_Float16)b;
    return __builtin_bit_cast(unsigned, h);
}
__device__ __forceinline__ h2_t as_h2(unsigned u) {
    return __builtin_bit_cast(h2_t, u);
}
__device__ __forceinline__ float fdot2(h2_t a, h2_t b, float c) {
#if __has_builtin(__builtin_amdgcn_fdot2)
    return __builtin_amdgcn_fdot2(a, b, c, false);
#else
    return (float)a.x * (float)b.x + (float)a.y * (float)b.y + c;
#endif
}

// ---------- pass 1: src [N,3,HS,WS] fp32 -> [N,HS,WS] 16B entries ----------
// entry(x) = { h2(c0[x],c0[x+1]), h2(c1[x],c1[x+1]), h2(c2[x],c2[x+1]), pad }
// (x+1 clamped to row end). One entry per thread: coalesced 4B reads (the +1
// read hits L1), one lane-coalesced 16B store.
__global__ __launch_bounds__(256) void pair_pack_kernel(
    const float* __restrict__ src, uint4* __restrict__ ws)
{
    const size_t HWs = (size_t)HS_ * WS_;
    size_t g = (size_t)blockIdx.x * blockDim.x + threadIdx.x;
    if (g >= (size_t)N_ * HWs) return;
    int n = (int)(g / HWs);
    size_t p = g - (size_t)n * HWs;
    int x = (int)(p % WS_);
    int dx = (x < WS_ - 1) ? 1 : 0;

    const float* s0 = src + (size_t)n * C_ * HWs + p;
    const float* s1 = s0 + HWs;
    const float* s2 = s1 + HWs;

    float c0a = s0[0], c0b = s0[dx];
    float c1a = s1[0], c1b = s1[dx];
    float c2a = s2[0], c2b = s2[dx];

    uint4 e;
    e.x = pack_h2(c0a, c0b);
    e.y = pack_h2(c1a, c1b);
    e.z = pack_h2(c2a, c2b);
    e.w = 0u;
    ws[g] = e;
}

// ---------- pass 2: warp + bilinear, 4 px/thread, 2 gathers/px ----------
__global__ __launch_bounds__(256) void warp_main4_kernel(
    const float* __restrict__ depth,   // [N,1,HD,WD]
    const uint4* __restrict__ wsrc,    // [N,HS,WS] paired entries
    const float* __restrict__ abc,     // [3,HD,WD]
    const float* __restrict__ tr,      // [3]
    const float* __restrict__ pin,     // [4]
    float* __restrict__ out)           // [N,C,HD,WD]
{
    const int HW = HD_ * WD_;
    int t = blockIdx.x * blockDim.x + threadIdx.x;
    int base = t * 4;
    if (base >= N_ * HW) return;

    int n  = base / HW;
    int hw = base - n * HW;

    f32x4 d4 = *(const f32x4*)(depth + base);
    f32x4 a4 = *(const f32x4*)(abc + hw);
    f32x4 b4 = *(const f32x4*)(abc + HW + hw);
    f32x4 c4 = *(const f32x4*)(abc + 2 * HW + hw);

    float tx = tr[0], ty = tr[1], tz = tr[2];
    float fu = pin[0], fv = pin[1], du = pin[2], dv = pin[3];

    const size_t HWs = (size_t)HS_ * WS_;
    const uint4* sn = wsrc + (size_t)n * HWs;

    f32x4 r0, r1, r2;

#pragma unroll
    for (int i = 0; i < 4; ++i) {
        float d = d4[i];
        float a = a4[i];
        float b = b4[i];
        float c = c4[i];

        float denom = c * d + tz;
        float inv = 1.0f / denom;
        float xx = (a * d + tx) * inv;
        float yy = (b * d + ty) * inv;
        float uu = fu * xx + du;
        float vv = fv * yy + dv;

        float gx = 2.0f * uu / (float)(WS_ - 1) - 1.0f;
        float gy = 2.0f * vv / (float)(HS_ - 1) - 1.0f;
        float x = ((gx + 1.0f) * (float)WS_ - 1.0f) * 0.5f;
        float y = ((gy + 1.0f) * (float)HS_ - 1.0f) * 0.5f;

        x = fminf(fmaxf(x, 0.0f), (float)(WS_ - 1));
        y = fminf(fmaxf(y, 0.0f), (float)(HS_ - 1));

        float x0f = floorf(x);
        float y0f = floorf(y);
        float wx = x - x0f;
        float wy = y - y0f;
        int x0 = (int)x0f;
        int y0 = (int)y0f;
        int y1 = min(y0 + 1, HS_ - 1);

        uint4 E0 = sn[(size_t)y0 * WS_ + x0];   // taps (y0,x0),(y0,x1)
        uint4 E1 = sn[(size_t)y1 * WS_ + x0];   // taps (y1,x0),(y1,x1)

        float w00 = (1.0f - wy) * (1.0f - wx);
        float w01 = (1.0f - wy) * wx;
        float w10 = wy * (1.0f - wx);
        float w11 = wy * wx;

        h2_t wA = { (_Float16)w00, (_Float16)w01 };
        h2_t wB = { (_Float16)w10, (_Float16)w11 };

        r0[i] = fdot2(as_h2(E0.x), wA, fdot2(as_h2(E1.x), wB, 0.0f));
        r1[i] = fdot2(as_h2(E0.y), wA, fdot2(as_h2(E1.y), wB, 0.0f));
        r2[i] = fdot2(as_h2(E0.z), wA, fdot2(as_h2(E1.z), wB, 0.0f));
    }

    float* on = out + (size_t)n * C_ * HW + hw;
    __builtin_nontemporal_store(r0, (f32x4*)(on));
    __builtin_nontemporal_store(r1, (f32x4*)(on + (size_t)HW));
    __builtin_nontemporal_store(r2, (f32x4*)(on + (size_t)2 * HW));
}

// ---------- fallback: planar (no workspace needed) ----------
__global__ __launch_bounds__(256) void warp_planar_kernel(
    const float* __restrict__ depth, const float* __restrict__ src,
    const float* __restrict__ abc, const float* __restrict__ tr,
    const float* __restrict__ pin, float* __restrict__ out)
{
    const int HW = HD_ * WD_;
    int idx = blockIdx.x * blockDim.x + threadIdx.x;
    if (idx >= N_ * HW) return;
    int n  = idx / HW;
    int hw = idx - n * HW;
    float d = depth[idx];
    float a = abc[hw];
    float b = abc[HW + hw];
    float c = abc[2 * HW + hw];
    float denom = c * d + tr[2];
    float inv = 1.0f / denom;
    float uu = pin[0] * ((a * d + tr[0]) * inv) + pin[2];
    float vv = pin[1] * ((b * d + tr[1]) * inv) + pin[3];
    float gx = 2.0f * uu / (float)(WS_ - 1) - 1.0f;
    float gy = 2.0f * vv / (float)(HS_ - 1) - 1.0f;
    float x = ((gx + 1.0f) * (float)WS_ - 1.0f) * 0.5f;
    float y = ((gy + 1.0f) * (float)HS_ - 1.0f) * 0.5f;
    x = fminf(fmaxf(x, 0.0f), (float)(WS_ - 1));
    y = fminf(fmaxf(y, 0.0f), (float)(HS_ - 1));
    float x0f = floorf(x), y0f = floorf(y);
    float wx = x - x0f, wy = y - y0f;
    int x0 = (int)x0f, y0 = (int)y0f;
    int x1 = min(x0 + 1, WS_ - 1);
    int y1 = min(y0 + 1, HS_ - 1);
    float w00 = (1.0f - wy) * (1.0f - wx), w01 = (1.0f - wy) * wx;
    float w10 = wy * (1.0f - wx), w11 = wy * wx;
    const size_t HWs = (size_t)HS_ * WS_;
    const float* sn = src + (size_t)n * C_ * HWs;
    int o00 = y0 * WS_ + x0, o01 = y0 * WS_ + x1;
    int o10 = y1 * WS_ + x0, o11 = y1 * WS_ + x1;
    float* on = out + (size_t)n * C_ * HW + hw;
#pragma unroll
    for (int ch = 0; ch < C_; ++ch) {
        const float* sc = sn + (size_t)ch * HWs;
        on[(size_t)ch * HW] = sc[o00] * w00 + sc[o01] * w01
                            + sc[o10] * w10 + sc[o11] * w11;
    }
}

extern "C" void kernel_launch(void* const* d_in, const int* in_sizes, int n_in,
                              void* d_out, int out_size, void* d_ws, size_t ws_size,
                              hipStream_t stream) {
    const float* depth = (const float*)d_in[0];
    const float* src   = (const float*)d_in[1];
    const float* abc   = (const float*)d_in[2];
    const float* tr    = (const float*)d_in[3];
    const float* pin   = (const float*)d_in[4];
    float* out = (float*)d_out;

    const size_t src_px = (size_t)N_ * HS_ * WS_;
    const size_t need = src_px * 16;  // 16B per paired entry
    const int total = N_ * HD_ * WD_;
    const int block = 256;

    if (ws_size >= need) {
        const int g1 = (int)((src_px + block - 1) / block);
        pair_pack_kernel<<<g1, block, 0, stream>>>(src, (uint4*)d_ws);
        const int g2 = (total / 4 + block - 1) / block;
        warp_main4_kernel<<<g2, block, 0, stream>>>(depth, (const uint4*)d_ws,
                                                    abc, tr, pin, out);
    } else {
        const int g = (total + block - 1) / block;
        warp_planar_kernel<<<g, block, 0, stream>>>(depth, src, abc, tr, pin, out);
    }
}

// Round 4
// 328.825 us; speedup vs baseline: 1.0322x; 1.0322x over previous
//
#include <hip/hip_runtime.h>

#define N_  8
#define C_  3
#define HD_ 1024
#define WD_ 1280
#define HS_ 800
#define WS_ 1280

typedef _Float16 h2_t __attribute__((ext_vector_type(2)));
typedef float f32x4 __attribute__((ext_vector_type(4)));
// 16B vector with relaxed (8B) alignment: entries are 8B, pair-loads land on 8B
// boundaries. gfx950 global loads tolerate 8B-aligned dwordx4; if the compiler
// splits it, we get 2x dwordx2 (== round-2 request count, no worse).
typedef unsigned int uint4_a8 __attribute__((ext_vector_type(4), aligned(8)));

__device__ __forceinline__ unsigned pack_h2(float a, float b) {
    h2_t h;
    h.x = (_Float16)a;
    h.y = (_Float16)b;
    return __builtin_bit_cast(unsigned, h);
}
__device__ __forceinline__ h2_t as_h2(unsigned u) {
    return __builtin_bit_cast(h2_t, u);
}

// ---------- pass 1: src [N,3,HS,WS] fp32 -> [N,HS,WS] 8B entries ----------
// entry(px) = { h2(c0,c1), h2(c2,pad) }  -- pure interleave, 4 px/thread.
__global__ __launch_bounds__(256) void pack_kernel(
    const float* __restrict__ src, uint2* __restrict__ ws)
{
    const size_t HWs = (size_t)HS_ * WS_;
    size_t t = (size_t)blockIdx.x * blockDim.x + threadIdx.x;
    size_t base = t * 4;
    if (base >= (size_t)N_ * HWs) return;
    int n = (int)(base / HWs);
    size_t p = base - (size_t)n * HWs;
    const float* s = src + (size_t)n * C_ * HWs + p;

    f32x4 c0 = __builtin_nontemporal_load((const f32x4*)(s));
    f32x4 c1 = __builtin_nontemporal_load((const f32x4*)(s + HWs));
    f32x4 c2 = __builtin_nontemporal_load((const f32x4*)(s + 2 * HWs));

    uint4 A, B;
    A.x = pack_h2(c0[0], c1[0]);
    A.y = pack_h2(c2[0], 0.0f);
    A.z = pack_h2(c0[1], c1[1]);
    A.w = pack_h2(c2[1], 0.0f);
    B.x = pack_h2(c0[2], c1[2]);
    B.y = pack_h2(c2[2], 0.0f);
    B.z = pack_h2(c0[3], c1[3]);
    B.w = pack_h2(c2[3], 0.0f);

    uint4* o = (uint4*)(ws + base);
    o[0] = A;
    o[1] = B;
}

// ---------- pass 2: warp + bilinear, 4 px/thread, 2x16B gathers/px ----------
__global__ __launch_bounds__(256) void warp_main4_kernel(
    const float* __restrict__ depth,   // [N,1,HD,WD]
    const uint2* __restrict__ wsrc,    // [N,HS,WS] 8B entries
    const float* __restrict__ abc,     // [3,HD,WD]
    const float* __restrict__ tr,      // [3]
    const float* __restrict__ pin,     // [4]
    float* __restrict__ out)           // [N,C,HD,WD]
{
    const int HW = HD_ * WD_;

    // XCD swizzle: grid = 10240 = 8 images x 1280 blocks. Route image k's
    // blocks to XCD k (blockIdx % 8 heuristic) so each XCD's L2 streams a
    // single image's src region instead of all 8 XCDs thrashing the same one.
    int bid = blockIdx.x;
    if ((gridDim.x & 7) == 0) {
        int per = gridDim.x >> 3;
        bid = (bid & 7) * per + (bid >> 3);
    }

    int t = bid * blockDim.x + threadIdx.x;
    int base = t * 4;
    if (base >= N_ * HW) return;

    int n  = base / HW;
    int hw = base - n * HW;

    f32x4 d4 = __builtin_nontemporal_load((const f32x4*)(depth + base));
    f32x4 a4 = __builtin_nontemporal_load((const f32x4*)(abc + hw));
    f32x4 b4 = __builtin_nontemporal_load((const f32x4*)(abc + HW + hw));
    f32x4 c4 = __builtin_nontemporal_load((const f32x4*)(abc + 2 * HW + hw));

    float tx = tr[0], ty = tr[1], tz = tr[2];
    float fu = pin[0], fv = pin[1], du = pin[2], dv = pin[3];

    const size_t HWs = (size_t)HS_ * WS_;
    const uint2* sn = wsrc + (size_t)n * HWs;

    f32x4 r0, r1, r2;

#pragma unroll
    for (int i = 0; i < 4; ++i) {
        float d = d4[i];
        float a = a4[i];
        float b = b4[i];
        float c = c4[i];

        float denom = c * d + tz;
        float inv = 1.0f / denom;
        float xx = (a * d + tx) * inv;
        float yy = (b * d + ty) * inv;
        float uu = fu * xx + du;
        float vv = fv * yy + dv;

        float gx = 2.0f * uu / (float)(WS_ - 1) - 1.0f;
        float gy = 2.0f * vv / (float)(HS_ - 1) - 1.0f;
        float x = ((gx + 1.0f) * (float)WS_ - 1.0f) * 0.5f;
        float y = ((gy + 1.0f) * (float)HS_ - 1.0f) * 0.5f;

        x = fminf(fmaxf(x, 0.0f), (float)(WS_ - 1));
        y = fminf(fmaxf(y, 0.0f), (float)(HS_ - 1));

        float x0f = floorf(x);
        float y0f = floorf(y);
        int x0 = (int)x0f;
        int y0 = (int)y0f;
        int y1 = min(y0 + 1, HS_ - 1);

        // border fold: when x0 == WS-1 the x1 tap coincides with x0 and its
        // weight is wx == 0; shifting the window left by one and adding the
        // shift to wx keeps the interpolation exact.
        int xa = min(x0, WS_ - 2);
        float wx = (x - x0f) + (float)(x0 - xa);
        float wy = y - y0f;

        uint4_a8 E0 = *(const uint4_a8*)(sn + (size_t)y0 * WS_ + xa);
        uint4_a8 E1 = *(const uint4_a8*)(sn + (size_t)y1 * WS_ + xa);

        h2_t p0a = as_h2(E0.x);  // c0,c1 @ (y0,xa)
        h2_t p0b = as_h2(E0.y);  // c2,_  @ (y0,xa)
        h2_t p0c = as_h2(E0.z);  // c0,c1 @ (y0,xa+1)
        h2_t p0d = as_h2(E0.w);  // c2,_  @ (y0,xa+1)
        h2_t p1a = as_h2(E1.x);
        h2_t p1b = as_h2(E1.y);
        h2_t p1c = as_h2(E1.z);
        h2_t p1d = as_h2(E1.w);

        float iwx = 1.0f - wx;
        float iwy = 1.0f - wy;

        float t0c0 = iwx * (float)p0a.x + wx * (float)p0c.x;
        float t0c1 = iwx * (float)p0a.y + wx * (float)p0c.y;
        float t0c2 = iwx * (float)p0b.x + wx * (float)p0d.x;
        float t1c0 = iwx * (float)p1a.x + wx * (float)p1c.x;
        float t1c1 = iwx * (float)p1a.y + wx * (float)p1c.y;
        float t1c2 = iwx * (float)p1b.x + wx * (float)p1d.x;

        r0[i] = iwy * t0c0 + wy * t1c0;
        r1[i] = iwy * t0c1 + wy * t1c1;
        r2[i] = iwy * t0c2 + wy * t1c2;
    }

    float* on = out + (size_t)n * C_ * HW + hw;
    __builtin_nontemporal_store(r0, (f32x4*)(on));
    __builtin_nontemporal_store(r1, (f32x4*)(on + (size_t)HW));
    __builtin_nontemporal_store(r2, (f32x4*)(on + (size_t)2 * HW));
}

// ---------- fallback: planar (no workspace needed) ----------
__global__ __launch_bounds__(256) void warp_planar_kernel(
    const float* __restrict__ depth, const float* __restrict__ src,
    const float* __restrict__ abc, const float* __restrict__ tr,
    const float* __restrict__ pin, float* __restrict__ out)
{
    const int HW = HD_ * WD_;
    int idx = blockIdx.x * blockDim.x + threadIdx.x;
    if (idx >= N_ * HW) return;
    int n  = idx / HW;
    int hw = idx - n * HW;
    float d = depth[idx];
    float a = abc[hw];
    float b = abc[HW + hw];
    float c = abc[2 * HW + hw];
    float denom = c * d + tr[2];
    float inv = 1.0f / denom;
    float uu = pin[0] * ((a * d + tr[0]) * inv) + pin[2];
    float vv = pin[1] * ((b * d + tr[1]) * inv) + pin[3];
    float gx = 2.0f * uu / (float)(WS_ - 1) - 1.0f;
    float gy = 2.0f * vv / (float)(HS_ - 1) - 1.0f;
    float x = ((gx + 1.0f) * (float)WS_ - 1.0f) * 0.5f;
    float y = ((gy + 1.0f) * (float)HS_ - 1.0f) * 0.5f;
    x = fminf(fmaxf(x, 0.0f), (float)(WS_ - 1));
    y = fminf(fmaxf(y, 0.0f), (float)(HS_ - 1));
    float x0f = floorf(x), y0f = floorf(y);
    float wx = x - x0f, wy = y - y0f;
    int x0 = (int)x0f, y0 = (int)y0f;
    int x1 = min(x0 + 1, WS_ - 1);
    int y1 = min(y0 + 1, HS_ - 1);
    float w00 = (1.0f - wy) * (1.0f - wx), w01 = (1.0f - wy) * wx;
    float w10 = wy * (1.0f - wx), w11 = wy * wx;
    const size_t HWs = (size_t)HS_ * WS_;
    const float* sn = src + (size_t)n * C_ * HWs;
    int o00 = y0 * WS_ + x0, o01 = y0 * WS_ + x1;
    int o10 = y1 * WS_ + x0, o11 = y1 * WS_ + x1;
    float* on = out + (size_t)n * C_ * HW + hw;
#pragma unroll
    for (int ch = 0; ch < C_; ++ch) {
        const float* sc = sn + (size_t)ch * HWs;
        on[(size_t)ch * HW] = sc[o00] * w00 + sc[o01] * w01
                            + sc[o10] * w10 + sc[o11] * w11;
    }
}

extern "C" void kernel_launch(void* const* d_in, const int* in_sizes, int n_in,
                              void* d_out, int out_size, void* d_ws, size_t ws_size,
                              hipStream_t stream) {
    const float* depth = (const float*)d_in[0];
    const float* src   = (const float*)d_in[1];
    const float* abc   = (const float*)d_in[2];
    const float* tr    = (const float*)d_in[3];
    const float* pin   = (const float*)d_in[4];
    float* out = (float*)d_out;

    const size_t src_px = (size_t)N_ * HS_ * WS_;
    const size_t need = src_px * 8;  // 8B per entry
    const int total = N_ * HD_ * WD_;
    const int block = 256;

    if (ws_size >= need) {
        const int g1 = (int)((src_px / 4 + block - 1) / block);
        pack_kernel<<<g1, block, 0, stream>>>(src, (uint2*)d_ws);
        const int g2 = (total / 4 + block - 1) / block;
        warp_main4_kernel<<<g2, block, 0, stream>>>(depth, (const uint2*)d_ws,
                                                    abc, tr, pin, out);
    } else {
        const int g = (total + block - 1) / block;
        warp_planar_kernel<<<g, block, 0, stream>>>(depth, src, abc, tr, pin, out);
    }
}